// Round 2
// baseline (159.873 us; speedup 1.0000x reference)
//
#include <hip/hip_runtime.h>
#include <stdint.h>

#define BATCH 16
#define TO 2048
#define TI 2048
#define DH 64
#define NITER (TI / 64)

typedef __attribute__((ext_vector_type(8))) short bf16x8;
typedef __attribute__((ext_vector_type(4))) float f32x4;

__device__ __forceinline__ unsigned short f2bf(float f) {
  uint32_t x = __float_as_uint(f);
  x += 0x7fffu + ((x >> 16) & 1u);   // RNE
  return (unsigned short)(x >> 16);
}

// Prologue: K fp32 -> bf16 (same [b][i][d] layout); V fp32 -> bf16 transposed [b][d][i].
__global__ __launch_bounds__(256) void convert_kv(
    const float* __restrict__ kg, const float* __restrict__ vg,
    unsigned short* __restrict__ k_bf, unsigned short* __restrict__ v_t) {
  __shared__ __align__(16) unsigned short vt[64][72];
  int b = blockIdx.y;
  int i0 = blockIdx.x * 64;
  int t = threadIdx.x;

  {
    const float4* src = (const float4*)(kg + ((size_t)b * TI + i0) * DH);
    ushort4* dst = (ushort4*)(k_bf + ((size_t)b * TI + i0) * DH);
#pragma unroll
    for (int u = 0; u < 4; ++u) {
      float4 f = src[t + 256 * u];
      ushort4 o;
      o.x = f2bf(f.x); o.y = f2bf(f.y); o.z = f2bf(f.z); o.w = f2bf(f.w);
      dst[t + 256 * u] = o;
    }
  }
  {
    const float4* src = (const float4*)(vg + ((size_t)b * TI + i0) * DH);
#pragma unroll
    for (int u = 0; u < 4; ++u) {
      int idx = t + 256 * u;
      int row = idx >> 4;
      int c4 = idx & 15;
      float4 f = src[idx];
      vt[c4 * 4 + 0][row] = f2bf(f.x);
      vt[c4 * 4 + 1][row] = f2bf(f.y);
      vt[c4 * 4 + 2][row] = f2bf(f.z);
      vt[c4 * 4 + 3][row] = f2bf(f.w);
    }
  }
  __syncthreads();
  {
    int dd = t >> 2, part = t & 3;
    ushort4* dst = (ushort4*)(v_t + ((size_t)b * DH + dd) * TI + i0 + part * 16);
#pragma unroll
    for (int u = 0; u < 4; ++u) {
      ushort4 o;
      o.x = vt[dd][part * 16 + u * 4 + 0];
      o.y = vt[dd][part * 16 + u * 4 + 1];
      o.z = vt[dd][part * 16 + u * 4 + 2];
      o.w = vt[dd][part * 16 + u * 4 + 3];
      dst[u] = o;
    }
  }
}

// Flash attention, S^T formulation, fixed-m softmax.
// BARRIER-FREE: K/V chunks are read as MFMA fragments DIRECTLY from global
// (L1/L2-resident: per-XCD KV working set = 1 MiB after the XCD swizzle;
// all 4 waves of a block share each 16 KiB chunk -> L1 re-serves them).
// No LDS double-buffer -> no __syncthreads -> waves free-run and self-
// stagger, keeping the mask HBM stream continuously subscribed instead of
// the lockstep burst-then-drain pattern. Only LDS use is the wave-private
// P^T round-trip (wave-synchronous, lgkmcnt-only, no barrier).
//
// Body for iteration IC; consumes mask regs MCUR, prefetches next
// iteration's mask into MNXT (static double-buffer: no reg-copy).
#define ATTN_BODY(IC, MCUR, MNXT)                                              \
  {                                                                            \
    if ((IC) < NITER - 1) {                                                    \
      _Pragma("unroll") for (int mt = 0; mt < 4; ++mt)                         \
          MNXT[mt] = *(const int4*)(mbase + mt * 16);                          \
      mbase += 64;                                                             \
    }                                                                          \
    /* K fragments straight from global (chunk IC) */                          \
    const unsigned short* kc = k_base + (size_t)(IC) * 64 * DH;                \
    bf16x8 kf[8];                                                              \
    _Pragma("unroll") for (int mt = 0; mt < 4; ++mt) {                         \
      const unsigned short* kr = kc + (mt * 16 + ln15) * DH + quad * 8;        \
      kf[2 * mt] = *(const bf16x8*)kr;                                         \
      kf[2 * mt + 1] = *(const bf16x8*)(kr + 32);                              \
    }                                                                          \
    /* S^T = K x Q */                                                          \
    f32x4 st[4];                                                               \
    _Pragma("unroll") for (int mt = 0; mt < 4; ++mt) {                         \
      f32x4 acc = (f32x4){0.f, 0.f, 0.f, 0.f};                                 \
      acc = __builtin_amdgcn_mfma_f32_16x16x32_bf16(kf[2 * mt], qf[0], acc, 0, 0, 0);     \
      acc = __builtin_amdgcn_mfma_f32_16x16x32_bf16(kf[2 * mt + 1], qf[1], acc, 0, 0, 0); \
      st[mt] = acc;                                                            \
    }                                                                          \
    /* mask + exp (fixed m = 0) + partial l + P^T -> LDS (wave-private) */     \
    _Pragma("unroll") for (int mt = 0; mt < 4; ++mt) {                         \
      float p0 = (MCUR[mt].x != 0) ? __expf(st[mt][0]) : 0.f;                  \
      float p1 = (MCUR[mt].y != 0) ? __expf(st[mt][1]) : 0.f;                  \
      float p2 = (MCUR[mt].z != 0) ? __expf(st[mt][2]) : 0.f;                  \
      float p3 = (MCUR[mt].w != 0) ? __expf(st[mt][3]) : 0.f;                  \
      l_part += (p0 + p1) + (p2 + p3);                                         \
      uint32_t lo = (uint32_t)f2bf(p0) | ((uint32_t)f2bf(p1) << 16);           \
      uint32_t hi = (uint32_t)f2bf(p2) | ((uint32_t)f2bf(p3) << 16);           \
      uint2 pk; pk.x = lo; pk.y = hi;                                          \
      *(uint2*)&p_row[wave][ln15][mt * 16 + quad * 4] = pk;                    \
    }                                                                          \
    /* P^T B-fragments (wave-synchronous LDS round-trip, no barrier) */        \
    bf16x8 pf0 = *(const bf16x8*)&p_row[wave][ln15][quad * 8];                 \
    bf16x8 pf1 = *(const bf16x8*)&p_row[wave][ln15][32 + quad * 8];            \
    /* V^T fragments straight from global; O^T += V^T x P^T */                 \
    const unsigned short* vc = v_base + (size_t)(IC) * 64;                     \
    _Pragma("unroll") for (int dt = 0; dt < 4; ++dt) {                         \
      const unsigned short* vr = vc + (size_t)(dt * 16 + ln15) * TI + quad * 8;\
      bf16x8 vf0 = *(const bf16x8*)vr;                                         \
      bf16x8 vf1 = *(const bf16x8*)(vr + 32);                                  \
      o_acc[dt] = __builtin_amdgcn_mfma_f32_16x16x32_bf16(vf0, pf0, o_acc[dt], 0, 0, 0); \
      o_acc[dt] = __builtin_amdgcn_mfma_f32_16x16x32_bf16(vf1, pf1, o_acc[dt], 0, 0, 0); \
    }                                                                          \
  }

__global__ __launch_bounds__(256) void attn_kernel(
    const float* __restrict__ q, const int* __restrict__ mask,
    const unsigned short* __restrict__ k_bf, const unsigned short* __restrict__ v_t,
    float* __restrict__ out) {
  __shared__ __align__(16) unsigned short p_row[4][16][72];  // per-wave [qrow][key]

  // XCD-aware bijective swizzle: gridDim.x = 512 = 8 XCDs x 64 slots.
  // Each XCD serves 2 batches -> its bf16 K/V working set (2 x 512 KiB)
  // stays L2-resident under the streaming mask traffic.
  int n = blockIdx.x;
  int xcd = n & 7;
  int slot = n >> 3;            // 0..63
  int b = (xcd << 1) | (slot >> 5);
  int o_blk = slot & 31;

  int t = threadIdx.x;
  int wave = t >> 6;
  int lane = t & 63;
  int ln15 = lane & 15;
  int quad = lane >> 4;

  int o0 = o_blk * 64 + wave * 16;
  int qrow = o0 + ln15;

  // Q B-fragments, scale 1/8 folded in
  bf16x8 qf[2];
  {
    const float* qp = q + ((size_t)b * TO + qrow) * DH;
#pragma unroll
    for (int kc = 0; kc < 2; ++kc) {
      int kk = kc * 32 + quad * 8;
      float4 f0 = *(const float4*)(qp + kk);
      float4 f1 = *(const float4*)(qp + kk + 4);
      bf16x8 a;
      a[0] = (short)f2bf(f0.x * 0.125f);
      a[1] = (short)f2bf(f0.y * 0.125f);
      a[2] = (short)f2bf(f0.z * 0.125f);
      a[3] = (short)f2bf(f0.w * 0.125f);
      a[4] = (short)f2bf(f1.x * 0.125f);
      a[5] = (short)f2bf(f1.y * 0.125f);
      a[6] = (short)f2bf(f1.z * 0.125f);
      a[7] = (short)f2bf(f1.w * 0.125f);
      qf[kc] = a;
    }
  }

  f32x4 o_acc[4];
#pragma unroll
  for (int dt = 0; dt < 4; ++dt) o_acc[dt] = (f32x4){0.f, 0.f, 0.f, 0.f};
  float l_part = 0.f;

  const unsigned short* k_base = k_bf + (size_t)b * TI * DH;
  const unsigned short* v_base = v_t + (size_t)b * DH * TI;
  const int* mbase = mask + ((size_t)b * TO + qrow) * TI + quad * 4;

  // mask for iter 0 (static double-buffer mv/mw, rotated by the x2 unroll)
  int4 mv[4], mw[4];
#pragma unroll
  for (int mt = 0; mt < 4; ++mt) mv[mt] = *(const int4*)(mbase + mt * 16);
  mbase += 64;

  for (int ic = 0; ic < NITER; ic += 2) {
    ATTN_BODY(ic, mv, mw)
    ATTN_BODY(ic + 1, mw, mv)
  }

  // epilogue
  l_part += __shfl_xor(l_part, 16);
  l_part += __shfl_xor(l_part, 32);
  float inv = 1.0f / l_part;
  float* orow = out + ((size_t)b * TO + qrow) * DH;
#pragma unroll
  for (int dt = 0; dt < 4; ++dt) {
    float4 vout;
    vout.x = o_acc[dt][0] * inv;
    vout.y = o_acc[dt][1] * inv;
    vout.z = o_acc[dt][2] * inv;
    vout.w = o_acc[dt][3] * inv;
    *(float4*)(orow + dt * 16 + quad * 4) = vout;
  }
}

extern "C" void kernel_launch(void* const* d_in, const int* in_sizes, int n_in,
                              void* d_out, int out_size, void* d_ws, size_t ws_size,
                              hipStream_t stream) {
  const float* q = (const float*)d_in[0];
  const float* k = (const float*)d_in[1];
  const float* v = (const float*)d_in[2];
  const int* mask = (const int*)d_in[3];

  unsigned short* k_bf = (unsigned short*)d_ws;             // 4 MB
  unsigned short* v_t = k_bf + (size_t)BATCH * TI * DH;     // 4 MB

  convert_kv<<<dim3(TI / 64, BATCH), 256, 0, stream>>>(k, v, k_bf, v_t);
  attn_kernel<<<dim3(TO / 64 * BATCH), 256, 0, stream>>>(q, mask, k_bf, v_t, (float*)d_out);
}

// Round 3
// 90.861 us; speedup vs baseline: 1.7595x; 1.7595x over previous
//
#include <hip/hip_runtime.h>
#include <stdint.h>

#define BATCH 16
#define TO 2048
#define TI 2048
#define DH 64
#define NITER2 16   // key chunks per wave-group (TI/2/64)

typedef __attribute__((ext_vector_type(8))) short bf16x8;
typedef __attribute__((ext_vector_type(4))) float f32x4;

__device__ __forceinline__ unsigned short f2bf(float f) {
  uint32_t x = __float_as_uint(f);
  x += 0x7fffu + ((x >> 16) & 1u);   // RNE
  return (unsigned short)(x >> 16);
}

// Prologue: K fp32 -> bf16 (same [b][i][d] layout); V fp32 -> bf16 transposed [b][d][i].
__global__ __launch_bounds__(256) void convert_kv(
    const float* __restrict__ kg, const float* __restrict__ vg,
    unsigned short* __restrict__ k_bf, unsigned short* __restrict__ v_t) {
  __shared__ __align__(16) unsigned short vt[64][72];
  int b = blockIdx.y;
  int i0 = blockIdx.x * 64;
  int t = threadIdx.x;

  {
    const float4* src = (const float4*)(kg + ((size_t)b * TI + i0) * DH);
    ushort4* dst = (ushort4*)(k_bf + ((size_t)b * TI + i0) * DH);
#pragma unroll
    for (int u = 0; u < 4; ++u) {
      float4 f = src[t + 256 * u];
      ushort4 o;
      o.x = f2bf(f.x); o.y = f2bf(f.y); o.z = f2bf(f.z); o.w = f2bf(f.w);
      dst[t + 256 * u] = o;
    }
  }
  {
    const float4* src = (const float4*)(vg + ((size_t)b * TI + i0) * DH);
#pragma unroll
    for (int u = 0; u < 4; ++u) {
      int idx = t + 256 * u;
      int row = idx >> 4;
      int c4 = idx & 15;
      float4 f = src[idx];
      vt[c4 * 4 + 0][row] = f2bf(f.x);
      vt[c4 * 4 + 1][row] = f2bf(f.y);
      vt[c4 * 4 + 2][row] = f2bf(f.z);
      vt[c4 * 4 + 3][row] = f2bf(f.w);
    }
  }
  __syncthreads();
  {
    int dd = t >> 2, part = t & 3;
    ushort4* dst = (ushort4*)(v_t + ((size_t)b * DH + dd) * TI + i0 + part * 16);
#pragma unroll
    for (int u = 0; u < 4; ++u) {
      ushort4 o;
      o.x = vt[dd][part * 16 + u * 4 + 0];
      o.y = vt[dd][part * 16 + u * 4 + 1];
      o.z = vt[dd][part * 16 + u * 4 + 2];
      o.w = vt[dd][part * 16 + u * 4 + 3];
      dst[u] = o;
    }
  }
}

// Flash attention, S^T formulation, fixed-m softmax (m = 0, safe: |S| bounded).
// OCCUPANCY VERSION: 512-thread blocks, 8 waves = 2 wave-GROUPS of 4.
// Group 0 processes keys [0,1024), group 1 keys [1024,2048) over the same
// 64 q-rows; unnormalized O and l partials simply ADD (fixed-m softmax),
// combined through LDS at the end. Per-group K/V chunk is single-buffered
// in LDS (2 lgkm-only barriers/iter, 16 iters = same 32 barriers as before)
// -> LDS 54 KB -> 2 blocks/CU -> 16 waves/CU (~50% occupancy), double the
// latency-hiding of the 4-wave version. All barriers drain lgkmcnt ONLY;
// global loads (mask + next KV chunk) stay in flight across them.
#define ATTN_BODY(IC, MCUR, MNXT)                                              \
  {                                                                            \
    if ((IC) < NITER2 - 1) {                                                   \
      _Pragma("unroll") for (int mt = 0; mt < 4; ++mt)                         \
          MNXT[mt] = *(const int4*)(mbase + mt * 16);                          \
      mbase += 64;                                                             \
    }                                                                          \
    /* S^T = K x Q on this group's chunk */                                    \
    f32x4 st[4];                                                               \
    _Pragma("unroll") for (int mt = 0; mt < 4; ++mt) {                         \
      bf16x8 kf0 = *(const bf16x8*)&k_lds[g][mt * 16 + ln15][quad * 8];        \
      bf16x8 kf1 = *(const bf16x8*)&k_lds[g][mt * 16 + ln15][32 + quad * 8];   \
      f32x4 acc = (f32x4){0.f, 0.f, 0.f, 0.f};                                 \
      acc = __builtin_amdgcn_mfma_f32_16x16x32_bf16(kf0, qf[0], acc, 0, 0, 0); \
      acc = __builtin_amdgcn_mfma_f32_16x16x32_bf16(kf1, qf[1], acc, 0, 0, 0); \
      st[mt] = acc;                                                            \
    }                                                                          \
    /* mask + exp (fixed m = 0) + partial l + P^T -> LDS (wave-private) */     \
    _Pragma("unroll") for (int mt = 0; mt < 4; ++mt) {                         \
      float p0 = (MCUR[mt].x != 0) ? __expf(st[mt][0]) : 0.f;                  \
      float p1 = (MCUR[mt].y != 0) ? __expf(st[mt][1]) : 0.f;                  \
      float p2 = (MCUR[mt].z != 0) ? __expf(st[mt][2]) : 0.f;                  \
      float p3 = (MCUR[mt].w != 0) ? __expf(st[mt][3]) : 0.f;                  \
      l_part += (p0 + p1) + (p2 + p3);                                         \
      uint32_t lo = (uint32_t)f2bf(p0) | ((uint32_t)f2bf(p1) << 16);           \
      uint32_t hi = (uint32_t)f2bf(p2) | ((uint32_t)f2bf(p3) << 16);           \
      uint2 pk; pk.x = lo; pk.y = hi;                                          \
      *(uint2*)&p_row[wave][ln15][mt * 16 + quad * 4] = pk;                    \
    }                                                                          \
    /* P^T B-fragments (wave-synchronous LDS round-trip, no barrier) */        \
    bf16x8 pf0 = *(const bf16x8*)&p_row[wave][ln15][quad * 8];                 \
    bf16x8 pf1 = *(const bf16x8*)&p_row[wave][ln15][32 + quad * 8];            \
    /* O^T += V^T x P^T */                                                     \
    _Pragma("unroll") for (int dt = 0; dt < 4; ++dt) {                         \
      bf16x8 vf0 = *(const bf16x8*)&v_lds[g][dt * 16 + ln15][quad * 8];        \
      bf16x8 vf1 = *(const bf16x8*)&v_lds[g][dt * 16 + ln15][32 + quad * 8];   \
      o_acc[dt] = __builtin_amdgcn_mfma_f32_16x16x32_bf16(vf0, pf0, o_acc[dt], 0, 0, 0); \
      o_acc[dt] = __builtin_amdgcn_mfma_f32_16x16x32_bf16(vf1, pf1, o_acc[dt], 0, 0, 0); \
    }                                                                          \
    /* all waves done reading chunk IC */                                      \
    asm volatile("s_waitcnt lgkmcnt(0)\n\ts_barrier" ::: "memory");            \
    if ((IC) < NITER2 - 1) {                                                   \
      /* stage chunk IC+1 (regs, loaded one full iter ago) */                  \
      *(uint4*)&k_lds[g][row][part * 16] = ka0;                                \
      *(uint4*)&k_lds[g][row][part * 16 + 8] = ka1;                            \
      *(uint4*)&v_lds[g][row][part * 16] = va0;                                \
      *(uint4*)&v_lds[g][row][part * 16 + 8] = va1;                            \
      /* issue chunk IC+2 loads (consumed after next compute phase) */         \
      if ((IC) < NITER2 - 2) {                                                 \
        ka0 = kp[0]; ka1 = kp[1];                                              \
        va0 = vp[0]; va1 = vp[1];                                              \
        kp = (const uint4*)((const char*)kp + 64 * DH * 2);                    \
        vp = (const uint4*)((const char*)vp + 64 * 2);                         \
      }                                                                        \
      /* writes visible to the group's 4 waves */                              \
      asm volatile("s_waitcnt lgkmcnt(0)\n\ts_barrier" ::: "memory");          \
    }                                                                          \
  }

__global__ __launch_bounds__(512) void attn_kernel(
    const float* __restrict__ q, const int* __restrict__ mask,
    const unsigned short* __restrict__ k_bf, const unsigned short* __restrict__ v_t,
    float* __restrict__ out) {
  __shared__ __align__(16) unsigned short k_lds[2][64][72];  // [group][key][dim]
  __shared__ __align__(16) unsigned short v_lds[2][64][72];  // [group][dim][key]
  __shared__ __align__(16) unsigned short p_row[8][16][72];  // per-wave [qrow][key]

  // XCD-aware bijective swizzle: gridDim.x = 512 = 8 XCDs x 64 slots.
  int n = blockIdx.x;
  int xcd = n & 7;
  int slot = n >> 3;            // 0..63
  int b = (xcd << 1) | (slot >> 5);
  int o_blk = slot & 31;

  int t = threadIdx.x;
  int wave = t >> 6;            // 0..7
  int g = wave >> 2;            // key-half group
  int w = wave & 3;             // wave within group
  int lane = t & 63;
  int ln15 = lane & 15;
  int quad = lane >> 4;

  int qrow = o_blk * 64 + w * 16 + ln15;

  // Q B-fragments, scale 1/8 folded in (both groups read the same Q rows)
  bf16x8 qf[2];
  {
    const float* qp = q + ((size_t)b * TO + qrow) * DH;
#pragma unroll
    for (int kc = 0; kc < 2; ++kc) {
      int kk = kc * 32 + quad * 8;
      float4 f0 = *(const float4*)(qp + kk);
      float4 f1 = *(const float4*)(qp + kk + 4);
      bf16x8 a;
      a[0] = (short)f2bf(f0.x * 0.125f);
      a[1] = (short)f2bf(f0.y * 0.125f);
      a[2] = (short)f2bf(f0.z * 0.125f);
      a[3] = (short)f2bf(f0.w * 0.125f);
      a[4] = (short)f2bf(f1.x * 0.125f);
      a[5] = (short)f2bf(f1.y * 0.125f);
      a[6] = (short)f2bf(f1.z * 0.125f);
      a[7] = (short)f2bf(f1.w * 0.125f);
      qf[kc] = a;
    }
  }

  f32x4 o_acc[4];
#pragma unroll
  for (int dt = 0; dt < 4; ++dt) o_acc[dt] = (f32x4){0.f, 0.f, 0.f, 0.f};
  float l_part = 0.f;

  // staging mapping: 256 threads per group stage that group's 64x64 chunk
  int tg = t & 255;
  int row = tg >> 2, part = tg & 3;
  const uint4* kp = (const uint4*)(k_bf + ((size_t)b * TI + g * 1024 + row) * DH + part * 16);
  const uint4* vp = (const uint4*)(v_t + ((size_t)b * DH + row) * TI + g * 1024 + part * 16);
  const int* mbase = mask + ((size_t)b * TO + qrow) * TI + g * 1024 + quad * 4;

  // ---- prologue ----
  // chunk 0 -> regs -> LDS
  uint4 ka0 = kp[0], ka1 = kp[1];
  uint4 va0 = vp[0], va1 = vp[1];
  kp = (const uint4*)((const char*)kp + 64 * DH * 2);
  vp = (const uint4*)((const char*)vp + 64 * 2);
  *(uint4*)&k_lds[g][row][part * 16] = ka0;
  *(uint4*)&k_lds[g][row][part * 16 + 8] = ka1;
  *(uint4*)&v_lds[g][row][part * 16] = va0;
  *(uint4*)&v_lds[g][row][part * 16 + 8] = va1;
  // chunk 1 -> regs (in flight across iter 0's compute)
  ka0 = kp[0]; ka1 = kp[1];
  va0 = vp[0]; va1 = vp[1];
  kp = (const uint4*)((const char*)kp + 64 * DH * 2);
  vp = (const uint4*)((const char*)vp + 64 * 2);
  // mask for iter 0 (static double-buffer mv/mw rotated by the x2 unroll)
  int4 mv[4], mw[4];
#pragma unroll
  for (int mt = 0; mt < 4; ++mt) mv[mt] = *(const int4*)(mbase + mt * 16);
  mbase += 64;
  asm volatile("s_waitcnt lgkmcnt(0)\n\ts_barrier" ::: "memory");

  for (int ic = 0; ic < NITER2; ic += 2) {
    ATTN_BODY(ic, mv, mw)
    ATTN_BODY(ic + 1, mw, mv)
  }
  // (loop ends with the IC=15 post-compute barrier: LDS reads all drained)

  // ---- combine the two key-half partials through LDS ----
  l_part += __shfl_xor(l_part, 16);
  l_part += __shfl_xor(l_part, 32);

  float* scr = (float*)&k_lds[0][0][0];    // [64][68] f32 = 17.4 KB (fits in k_lds)
  float* lscr = (float*)&p_row[0][0][0];   // 64 f32
  int orow_i = w * 16 + ln15;              // row within the block's 64 q-rows

  if (g == 1) {
#pragma unroll
    for (int dt = 0; dt < 4; ++dt)
      *(f32x4*)&scr[(size_t)orow_i * 68 + dt * 16 + quad * 4] = o_acc[dt];
    if (quad == 0) lscr[orow_i] = l_part;
  }
  asm volatile("s_waitcnt lgkmcnt(0)\n\ts_barrier" ::: "memory");
  if (g == 0) {
    float inv = 1.0f / (l_part + lscr[orow_i]);
    float* orow = out + ((size_t)b * TO + qrow) * DH;
#pragma unroll
    for (int dt = 0; dt < 4; ++dt) {
      f32x4 other = *(const f32x4*)&scr[(size_t)orow_i * 68 + dt * 16 + quad * 4];
      float4 vout;
      vout.x = (o_acc[dt][0] + other[0]) * inv;
      vout.y = (o_acc[dt][1] + other[1]) * inv;
      vout.z = (o_acc[dt][2] + other[2]) * inv;
      vout.w = (o_acc[dt][3] + other[3]) * inv;
      *(float4*)(orow + dt * 16 + quad * 4) = vout;
    }
  }
}

extern "C" void kernel_launch(void* const* d_in, const int* in_sizes, int n_in,
                              void* d_out, int out_size, void* d_ws, size_t ws_size,
                              hipStream_t stream) {
  const float* q = (const float*)d_in[0];
  const float* k = (const float*)d_in[1];
  const float* v = (const float*)d_in[2];
  const int* mask = (const int*)d_in[3];

  unsigned short* k_bf = (unsigned short*)d_ws;             // 4 MB
  unsigned short* v_t = k_bf + (size_t)BATCH * TI * DH;     // 4 MB

  convert_kv<<<dim3(TI / 64, BATCH), 256, 0, stream>>>(k, v, k_bf, v_t);
  attn_kernel<<<dim3(TO / 64 * BATCH), 512, 0, stream>>>(q, mask, k_bf, v_t, (float*)d_out);
}

// Round 4
// 81.292 us; speedup vs baseline: 1.9666x; 1.1177x over previous
//
#include <hip/hip_runtime.h>
#include <stdint.h>

#define BATCH 16
#define TO 2048
#define TI 2048
#define DH 64
#define NITER2 16   // key chunks per wave-group (TI/2/64)

typedef __attribute__((ext_vector_type(8))) short bf16x8;
typedef __attribute__((ext_vector_type(4))) float f32x4;

__device__ __forceinline__ unsigned short f2bf(float f) {
  uint32_t x = __float_as_uint(f);
  x += 0x7fffu + ((x >> 16) & 1u);   // RNE
  return (unsigned short)(x >> 16);
}

// Prologue: K fp32 -> bf16 (same [b][i][d] layout); V fp32 -> bf16 transposed [b][d][i].
__global__ __launch_bounds__(256) void convert_kv(
    const float* __restrict__ kg, const float* __restrict__ vg,
    unsigned short* __restrict__ k_bf, unsigned short* __restrict__ v_t) {
  __shared__ __align__(16) unsigned short vt[64][72];
  int b = blockIdx.y;
  int i0 = blockIdx.x * 64;
  int t = threadIdx.x;

  {
    const float4* src = (const float4*)(kg + ((size_t)b * TI + i0) * DH);
    ushort4* dst = (ushort4*)(k_bf + ((size_t)b * TI + i0) * DH);
#pragma unroll
    for (int u = 0; u < 4; ++u) {
      float4 f = src[t + 256 * u];
      ushort4 o;
      o.x = f2bf(f.x); o.y = f2bf(f.y); o.z = f2bf(f.z); o.w = f2bf(f.w);
      dst[t + 256 * u] = o;
    }
  }
  {
    const float4* src = (const float4*)(vg + ((size_t)b * TI + i0) * DH);
#pragma unroll
    for (int u = 0; u < 4; ++u) {
      int idx = t + 256 * u;
      int row = idx >> 4;
      int c4 = idx & 15;
      float4 f = src[idx];
      vt[c4 * 4 + 0][row] = f2bf(f.x);
      vt[c4 * 4 + 1][row] = f2bf(f.y);
      vt[c4 * 4 + 2][row] = f2bf(f.z);
      vt[c4 * 4 + 3][row] = f2bf(f.w);
    }
  }
  __syncthreads();
  {
    int dd = t >> 2, part = t & 3;
    ushort4* dst = (ushort4*)(v_t + ((size_t)b * DH + dd) * TI + i0 + part * 16);
#pragma unroll
    for (int u = 0; u < 4; ++u) {
      ushort4 o;
      o.x = vt[dd][part * 16 + u * 4 + 0];
      o.y = vt[dd][part * 16 + u * 4 + 1];
      o.z = vt[dd][part * 16 + u * 4 + 2];
      o.w = vt[dd][part * 16 + u * 4 + 3];
      dst[u] = o;
    }
  }
}

// Flash attention, S^T formulation, fixed-m softmax (m = 0, safe: |S| bounded).
// R1 pipeline (double-buffered LDS, ONE lgkm-only barrier/iter, staging
// overlapped with compute) + in-block 2-way key split for occupancy:
// 512-thread blocks, 8 waves = 2 groups of 4; group g handles keys
// [g*1024,(g+1)*1024). Unnormalized O and l partials ADD (fixed-m),
// combined through LDS at the end. LDS tiles are EXACT 64x64 (no pad) with
// T2 XOR swizzle (16B unit ^= row&7) -> 80 KB total -> 2 blocks/CU ->
// 16 waves/CU (4/SIMD), 2x the latency hiding of R1.
#define ATTN_BODY(CUR, IC, MCUR, MNXT)                                         \
  {                                                                            \
    if ((IC) < NITER2 - 1) {                                                   \
      _Pragma("unroll") for (int mt = 0; mt < 4; ++mt)                         \
          MNXT[mt] = *(const int4*)(mbase + mt * 16);                          \
      mbase += 64;                                                             \
      /* stage chunk IC+1 (regs, loaded one full iter ago) into other buf */   \
      {                                                                        \
        unsigned short* kd = &k_lds[g][(CUR) ^ 1][row][0];                     \
        unsigned short* vd = &v_lds[g][(CUR) ^ 1][row][0];                     \
        int h = row & 7;                                                       \
        *(uint4*)(kd + ((((2 * part) ^ h) << 3))) = ka0;                       \
        *(uint4*)(kd + ((((2 * part + 1) ^ h) << 3))) = ka1;                   \
        *(uint4*)(vd + ((((2 * part) ^ h) << 3))) = va0;                       \
        *(uint4*)(vd + ((((2 * part + 1) ^ h) << 3))) = va1;                   \
      }                                                                        \
    }                                                                          \
    /* issue chunk IC+2 loads (drain: next iter's LDS-write use) */            \
    if ((IC) < NITER2 - 2) {                                                   \
      ka0 = kp[0]; ka1 = kp[1];                                                \
      va0 = vp[0]; va1 = vp[1];                                                \
      kp = (const uint4*)((const char*)kp + 64 * DH * 2);                      \
      vp = (const uint4*)((const char*)vp + 64 * 2);                           \
    }                                                                          \
    /* S^T = K x Q on buf[CUR] (swizzled reads: unit ^ (row&7)) */             \
    f32x4 st[4];                                                               \
    _Pragma("unroll") for (int mt = 0; mt < 4; ++mt) {                         \
      const unsigned short* kr = &k_lds[g][CUR][mt * 16 + ln15][0];            \
      bf16x8 kf0 = *(const bf16x8*)(kr + ((quad ^ hq) << 3));                  \
      bf16x8 kf1 = *(const bf16x8*)(kr + (((4 + quad) ^ hq) << 3));            \
      f32x4 acc = (f32x4){0.f, 0.f, 0.f, 0.f};                                 \
      acc = __builtin_amdgcn_mfma_f32_16x16x32_bf16(kf0, qf[0], acc, 0, 0, 0); \
      acc = __builtin_amdgcn_mfma_f32_16x16x32_bf16(kf1, qf[1], acc, 0, 0, 0); \
      st[mt] = acc;                                                            \
    }                                                                          \
    /* mask + exp (fixed m = 0) + partial l + P^T -> LDS (wave-private) */     \
    _Pragma("unroll") for (int mt = 0; mt < 4; ++mt) {                         \
      float p0 = (MCUR[mt].x != 0) ? __expf(st[mt][0]) : 0.f;                  \
      float p1 = (MCUR[mt].y != 0) ? __expf(st[mt][1]) : 0.f;                  \
      float p2 = (MCUR[mt].z != 0) ? __expf(st[mt][2]) : 0.f;                  \
      float p3 = (MCUR[mt].w != 0) ? __expf(st[mt][3]) : 0.f;                  \
      l_part += (p0 + p1) + (p2 + p3);                                         \
      uint32_t lo = (uint32_t)f2bf(p0) | ((uint32_t)f2bf(p1) << 16);           \
      uint32_t hi = (uint32_t)f2bf(p2) | ((uint32_t)f2bf(p3) << 16);           \
      uint2 pk; pk.x = lo; pk.y = hi;                                          \
      *(uint2*)&p_row[wave][ln15][(((2 * mt + (quad >> 1)) ^ hq) << 3) +       \
                                  ((quad & 1) << 2)] = pk;                     \
    }                                                                          \
    /* P^T B-fragments (wave-synchronous LDS round-trip, no barrier) */        \
    bf16x8 pf0 = *(const bf16x8*)&p_row[wave][ln15][(quad ^ hq) << 3];         \
    bf16x8 pf1 = *(const bf16x8*)&p_row[wave][ln15][((4 + quad) ^ hq) << 3];   \
    /* O^T += V^T x P^T on buf[CUR] */                                         \
    _Pragma("unroll") for (int dt = 0; dt < 4; ++dt) {                         \
      const unsigned short* vr = &v_lds[g][CUR][dt * 16 + ln15][0];            \
      bf16x8 vf0 = *(const bf16x8*)(vr + ((quad ^ hq) << 3));                  \
      bf16x8 vf1 = *(const bf16x8*)(vr + (((4 + quad) ^ hq) << 3));            \
      o_acc[dt] = __builtin_amdgcn_mfma_f32_16x16x32_bf16(vf0, pf0, o_acc[dt], 0, 0, 0); \
      o_acc[dt] = __builtin_amdgcn_mfma_f32_16x16x32_bf16(vf1, pf1, o_acc[dt], 0, 0, 0); \
    }                                                                          \
    /* single barrier: protects next iter's reads of buf[CUR^1] (written      \
       above) and next iter's writes of buf[CUR] (read above) */               \
    asm volatile("s_waitcnt lgkmcnt(0)\n\ts_barrier" ::: "memory");            \
  }

__global__ __launch_bounds__(512, 4) void attn_kernel(
    const float* __restrict__ q, const int* __restrict__ mask,
    const unsigned short* __restrict__ k_bf, const unsigned short* __restrict__ v_t,
    float* __restrict__ out) {
  // exact-size tiles + XOR swizzle: 32K + 32K + 16K = 80 KB -> 2 blocks/CU
  __shared__ __align__(16) unsigned short k_lds[2][2][64][64];  // [grp][buf][key][dim]
  __shared__ __align__(16) unsigned short v_lds[2][2][64][64];  // [grp][buf][dim][key]
  __shared__ __align__(16) unsigned short p_row[8][16][64];     // per-wave [qrow][key]

  // XCD-aware bijective swizzle: gridDim.x = 512 = 8 XCDs x 64 slots.
  int n = blockIdx.x;
  int xcd = n & 7;
  int slot = n >> 3;            // 0..63
  int b = (xcd << 1) | (slot >> 5);
  int o_blk = slot & 31;

  int t = threadIdx.x;
  int wave = t >> 6;            // 0..7
  int g = wave >> 2;            // key-half group
  int w = wave & 3;             // wave within group
  int lane = t & 63;
  int ln15 = lane & 15;
  int quad = lane >> 4;
  int hq = ln15 & 7;            // row-swizzle key for fragment reads

  int qrow = o_blk * 64 + w * 16 + ln15;

  // Q B-fragments, scale 1/8 folded in (both groups read the same Q rows)
  bf16x8 qf[2];
  {
    const float* qp = q + ((size_t)b * TO + qrow) * DH;
#pragma unroll
    for (int kc = 0; kc < 2; ++kc) {
      int kk = kc * 32 + quad * 8;
      float4 f0 = *(const float4*)(qp + kk);
      float4 f1 = *(const float4*)(qp + kk + 4);
      bf16x8 a;
      a[0] = (short)f2bf(f0.x * 0.125f);
      a[1] = (short)f2bf(f0.y * 0.125f);
      a[2] = (short)f2bf(f0.z * 0.125f);
      a[3] = (short)f2bf(f0.w * 0.125f);
      a[4] = (short)f2bf(f1.x * 0.125f);
      a[5] = (short)f2bf(f1.y * 0.125f);
      a[6] = (short)f2bf(f1.z * 0.125f);
      a[7] = (short)f2bf(f1.w * 0.125f);
      qf[kc] = a;
    }
  }

  f32x4 o_acc[4];
#pragma unroll
  for (int dt = 0; dt < 4; ++dt) o_acc[dt] = (f32x4){0.f, 0.f, 0.f, 0.f};
  float l_part = 0.f;

  // staging mapping: each group's 256 threads stage that group's 64x64 chunk
  int tg = t & 255;
  int row = tg >> 2, part = tg & 3;
  const uint4* kp = (const uint4*)(k_bf + ((size_t)b * TI + g * 1024 + row) * DH + part * 16);
  const uint4* vp = (const uint4*)(v_t + ((size_t)b * DH + row) * TI + g * 1024 + part * 16);
  const int* mbase = mask + ((size_t)b * TO + qrow) * TI + g * 1024 + quad * 4;

  // ---- pipeline prologue ----
  // chunk 0 -> regs -> buf0 (swizzled)
  uint4 ka0 = kp[0], ka1 = kp[1];
  uint4 va0 = vp[0], va1 = vp[1];
  kp = (const uint4*)((const char*)kp + 64 * DH * 2);
  vp = (const uint4*)((const char*)vp + 64 * 2);
  {
    unsigned short* kd = &k_lds[g][0][row][0];
    unsigned short* vd = &v_lds[g][0][row][0];
    int h = row & 7;
    *(uint4*)(kd + (((2 * part) ^ h) << 3)) = ka0;
    *(uint4*)(kd + (((2 * part + 1) ^ h) << 3)) = ka1;
    *(uint4*)(vd + (((2 * part) ^ h) << 3)) = va0;
    *(uint4*)(vd + (((2 * part + 1) ^ h) << 3)) = va1;
  }
  // chunk 1 -> regs (in flight across iter 0's compute)
  ka0 = kp[0]; ka1 = kp[1];
  va0 = vp[0]; va1 = vp[1];
  kp = (const uint4*)((const char*)kp + 64 * DH * 2);
  vp = (const uint4*)((const char*)vp + 64 * 2);
  // mask for iter 0 (static double-buffer mv/mw rotated by the x2 unroll)
  int4 mv[4], mw[4];
#pragma unroll
  for (int mt = 0; mt < 4; ++mt) mv[mt] = *(const int4*)(mbase + mt * 16);
  mbase += 64;
  asm volatile("s_waitcnt lgkmcnt(0)\n\ts_barrier" ::: "memory");

  for (int ic = 0; ic < NITER2; ic += 2) {
    ATTN_BODY(0, ic, mv, mw)
    ATTN_BODY(1, ic + 1, mw, mv)
  }
  // (loop ends with the IC=15 barrier: all LDS reads drained)

  // ---- combine the two key-half partials through LDS ----
  l_part += __shfl_xor(l_part, 16);
  l_part += __shfl_xor(l_part, 32);

  float* scr = (float*)&k_lds[0][0][0][0];  // [64][68] f32 = 17.4 KB (K dead)
  float* lscr = (float*)&p_row[0][0][0];    // 64 f32
  int orow_i = w * 16 + ln15;               // row within the block's 64 q-rows

  if (g == 1) {
#pragma unroll
    for (int dt = 0; dt < 4; ++dt)
      *(f32x4*)&scr[(size_t)orow_i * 68 + dt * 16 + quad * 4] = o_acc[dt];
    if (quad == 0) lscr[orow_i] = l_part;
  }
  asm volatile("s_waitcnt lgkmcnt(0)\n\ts_barrier" ::: "memory");
  if (g == 0) {
    float inv = 1.0f / (l_part + lscr[orow_i]);
    float* orow = out + ((size_t)b * TO + qrow) * DH;
#pragma unroll
    for (int dt = 0; dt < 4; ++dt) {
      f32x4 other = *(const f32x4*)&scr[(size_t)orow_i * 68 + dt * 16 + quad * 4];
      float4 vout;
      vout.x = (o_acc[dt][0] + other[0]) * inv;
      vout.y = (o_acc[dt][1] + other[1]) * inv;
      vout.z = (o_acc[dt][2] + other[2]) * inv;
      vout.w = (o_acc[dt][3] + other[3]) * inv;
      *(float4*)(orow + dt * 16 + quad * 4) = vout;
    }
  }
}

extern "C" void kernel_launch(void* const* d_in, const int* in_sizes, int n_in,
                              void* d_out, int out_size, void* d_ws, size_t ws_size,
                              hipStream_t stream) {
  const float* q = (const float*)d_in[0];
  const float* k = (const float*)d_in[1];
  const float* v = (const float*)d_in[2];
  const int* mask = (const int*)d_in[3];

  unsigned short* k_bf = (unsigned short*)d_ws;             // 4 MB
  unsigned short* v_t = k_bf + (size_t)BATCH * TI * DH;     // 4 MB

  convert_kv<<<dim3(TI / 64, BATCH), 256, 0, stream>>>(k, v, k_bf, v_t);
  attn_kernel<<<dim3(TO / 64 * BATCH), 512, 0, stream>>>(q, mask, k_bf, v_t, (float*)d_out);
}